// Round 1
// baseline (388.361 us; speedup 1.0000x reference)
//
#include <hip/hip_runtime.h>
#include <math.h>

#define B_    32
#define C_    64
#define T_    512
#define NROWS (B_ * C_)
#define CMAX_ 16
#define FEPS  1.1920929e-07f

__device__ __forceinline__ float gelu_exact(float x) {
    return 0.5f * x * (1.0f + erff(x * 0.7071067811865475f));
}

// One block (512 threads) per row r in [0, 2048).
// Phases: load row -> twiddle table -> DFT amp -> top-3 -> fold+conv+pool.
__global__ __launch_bounds__(512) void row_kernel(
    const float* __restrict__ feat,
    const float* __restrict__ w0, const float* __restrict__ b0,
    const float* __restrict__ w1, const float* __restrict__ b1,
    const float* __restrict__ w2, const float* __restrict__ b2,
    const float* __restrict__ wpj, const float* __restrict__ bpj,
    const float* __restrict__ wr, const float* __restrict__ br,
    float* __restrict__ avg_out, float* __restrict__ max_out,
    float* __restrict__ seq_out)
{
    __shared__ __align__(16) float row[T_];
    __shared__ float2 tw[T_];
    __shared__ float rep[512], imp[512];
    __shared__ float amp[257];
    __shared__ float WeffS[3][5][5];
    __shared__ float scal[8];
    __shared__ int   iparam[9];   // P[3], cyc[3], base[3]
    __shared__ float bwv[3];

    const int tid = threadIdx.x;
    const int r = blockIdx.x;

    row[tid] = feat[r * T_ + tid];
    {
        float sv, cv;
        sincosf((float)tid * 0.012271846303085130f, &sv, &cv); // 2*pi/512
        tw[tid] = make_float2(cv, sv);
    }
    if (tid < 75) {
        int k = tid / 25, ij = tid % 25, i = ij / 5, j = ij % 5;
        float w = wpj[2] * w2[k * 25 + i * 5 + j];
        if (i >= 1 && i <= 3 && j >= 1 && j <= 3)
            w += wpj[1] * w1[k * 9 + (i - 1) * 3 + (j - 1)];
        if (i == 2 && j == 2) w += wpj[0] * w0[k];
        WeffS[k][i][j] = w;
    } else if (tid == 80) {
        scal[0] = wpj[0] * b0[0] + wpj[1] * b1[0] + wpj[2] * b2[0] + bpj[0];
        scal[1] = wr[0]; scal[2] = wr[1]; scal[3] = wr[2]; scal[4] = br[0];
    } else if (tid == 81) {
        amp[0] = 0.0f;
    }
    __syncthreads();

    // ---- DFT: 256 freqs x 2 half-sums ----
    {
        const int f = 1 + (tid & 255);
        const int t0 = (tid >> 8) * 256;
        float re = 0.f, im = 0.f;
        int ph = (f * t0) & 511;
        const float4* row4 = reinterpret_cast<const float4*>(row);
        for (int t4 = (t0 >> 2); t4 < (t0 >> 2) + 64; ++t4) {
            float4 xv = row4[t4];
            float xs0 = xv.x, xs1 = xv.y, xs2 = xv.z, xs3 = xv.w;
            float2 wv;
            wv = tw[ph]; re = fmaf(xs0, wv.x, re); im = fmaf(-xs0, wv.y, im); ph = (ph + f) & 511;
            wv = tw[ph]; re = fmaf(xs1, wv.x, re); im = fmaf(-xs1, wv.y, im); ph = (ph + f) & 511;
            wv = tw[ph]; re = fmaf(xs2, wv.x, re); im = fmaf(-xs2, wv.y, im); ph = (ph + f) & 511;
            wv = tw[ph]; re = fmaf(xs3, wv.x, re); im = fmaf(-xs3, wv.y, im); ph = (ph + f) & 511;
        }
        rep[tid] = re; imp[tid] = im;
    }
    __syncthreads();
    if (tid < 256) {
        float rr = rep[tid] + rep[tid + 256];
        float ii = imp[tid] + imp[tid + 256];
        amp[tid + 1] = sqrtf(rr * rr + ii * ii);
    }
    __syncthreads();

    // ---- top-3 (jax.lax.top_k semantics: descending, ties -> lower index) ----
    if (tid == 0) {
        float vals[3]; int idxs[3];
        for (int kk = 0; kk < 3; ++kk) {
            float best = -1.0f; int bi = 0;
            for (int fq = 0; fq <= 256; ++fq) {
                float a = amp[fq];
                if (a > best) { best = a; bi = fq; }
            }
            vals[kk] = best; idxs[kk] = bi;
            amp[bi] = -2.0f;
        }
        float m = fmaxf(vals[0], fmaxf(vals[1], vals[2]));
        float e0 = expf(vals[0] - m), e1 = expf(vals[1] - m), e2 = expf(vals[2] - m);
        float inv = 1.0f / (e0 + e1 + e2);
        bwv[0] = e0 * inv; bwv[1] = e1 * inv; bwv[2] = e2 * inv;
        for (int kk = 0; kk < 3; ++kk) {
            int fi = idxs[kk] < 1 ? 1 : idxs[kk];
            int P = T_ / fi;
            P = P < 32 ? 32 : (P > 512 ? 512 : P);
            int cyc = T_ / P;
            int bs = T_ - cyc * P;
            iparam[kk] = P; iparam[3 + kk] = cyc; iparam[6 + kk] = bs;
        }
    }
    __syncthreads();

    // ---- fold + conv + pools ----
    const int P0 = iparam[0], P1 = iparam[1], P2 = iparam[2];
    const int cy0 = iparam[3], cy1 = iparam[4], cy2 = iparam[5];
    const int bs0 = iparam[6], bs1 = iparam[7], bs2 = iparam[8];
    const float beff = scal[0], wr0 = scal[1], wr1 = scal[2], wr2 = scal[3], bres = scal[4];
    const int p = tid;

    // pull Weff into registers (broadcast reads once, reused 16x)
    float We[3][5][5];
    #pragma unroll
    for (int k = 0; k < 3; ++k)
        #pragma unroll
        for (int i = 0; i < 5; ++i)
            #pragma unroll
            for (int j = 0; j < 5; ++j)
                We[k][i][j] = WeffS[k][i][j];

    const int Pk[3]  = {P0, P1, P2};
    const int cyk[3] = {cy0, cy1, cy2};
    const int bsk[3] = {bs0, bs1, bs2};

    float avg_num = 0.f, den = 0.f, mx = -3.402823466e38f;
    int anyv = 0;

    for (int cc = 0; cc < CMAX_; ++cc) {
        float zpre = beff;
        #pragma unroll
        for (int k = 0; k < 3; ++k) {
            const int P = Pk[k], cy = cyk[k], bs = bsk[k];
            #pragma unroll
            for (int dh = -2; dh <= 2; ++dh) {
                int hh = cc + dh;
                if ((unsigned)hh < 16u && hh < cy) {   // uniform across lanes
                    int off = bs + hh * P;
                    #pragma unroll
                    for (int dw = -2; dw <= 2; ++dw) {
                        int pp = p + dw;
                        int a = off + pp;
                        a = a < 0 ? 0 : (a > 511 ? 511 : a);
                        float v = ((unsigned)pp < (unsigned)P) ? row[a] : 0.f;
                        zpre = fmaf(We[k][dh + 2][dw + 2], v, zpre);
                    }
                }
            }
        }
        int m0 = (cc < cy0) & (p < P0);
        int m1 = (cc < cy1) & (p < P1);
        int m2 = (cc < cy2) & (p < P2);
        int a0 = bs0 + cc * P0 + p; a0 = a0 > 511 ? 511 : a0;
        int a1 = bs1 + cc * P1 + p; a1 = a1 > 511 ? 511 : a1;
        int a2 = bs2 + cc * P2 + p; a2 = a2 > 511 ? 511 : a2;
        float x0 = m0 ? row[a0] : 0.f;
        float x1 = m1 ? row[a1] : 0.f;
        float x2 = m2 ? row[a2] : 0.f;
        float res = fmaf(wr0, x0, fmaf(wr1, x1, fmaf(wr2, x2, bres)));
        float z = gelu_exact(zpre) + res;
        int mm = m0 | m1 | m2;
        float cm = mm ? 1.f : 0.f;
        avg_num += z * cm;
        den += cm;
        mx = mm ? fmaxf(mx, z) : mx;
        anyv |= mm;
    }
    float avg = avg_num / (den + FEPS);
    float mpool = anyv ? mx : 0.f;

    // seq_recon
    float seq = 0.f;
    #pragma unroll
    for (int k = 0; k < 3; ++k) {
        const int P = Pk[k], cy = cyk[k], bs = bsk[k];
        float s = 0.f;
        for (int c2 = 0; c2 < cy; ++c2) {   // cy is lane-uniform
            int a = bs + c2 * P + p; a = a > 511 ? 511 : a;
            s += ((p < P) ? row[a] : 0.f);
        }
        float brk = (p < P) ? s / ((float)cy + FEPS) : 0.f;
        seq = fmaf(bwv[k], brk, seq);
    }

    avg_out[r * T_ + p] = avg;
    max_out[r * T_ + p] = mpool;
    seq_out[r * T_ + p] = seq;
}

// out[b,o,t] = gelu( sum_{c'} wf[o,c'] * comb[b,c',t] + bf[o] )
// comb channels: [avg(64) | max(64) | seq(64)]
// block: 128 threads, tile 64o x 128t, micro-tile 8x8, c' chunked by source buffer.
__global__ __launch_bounds__(128) void fuse_kernel(
    const float* __restrict__ avgb, const float* __restrict__ maxb,
    const float* __restrict__ seqb,
    const float* __restrict__ wf, const float* __restrict__ bfu,
    float* __restrict__ out)
{
    __shared__ float wT[64][65];    // wT[c][o]
    __shared__ float Bt[64][132];   // Bt[c][t]
    const int tid = threadIdx.x;
    const int b = blockIdx.y;
    const int tt0 = blockIdx.x * 128;
    const int og = tid >> 4;        // 0..7
    const int tg = tid & 15;        // 0..15
    const int o0 = og * 8;
    const int t0 = tg * 8;

    float acc[8][8];
    #pragma unroll
    for (int i = 0; i < 8; ++i)
        #pragma unroll
        for (int j = 0; j < 8; ++j) acc[i][j] = 0.f;

    const float* srcs[3] = {avgb, maxb, seqb};
    for (int g = 0; g < 3; ++g) {
        const float* __restrict__ src = srcs[g];
        for (int i = tid; i < 64 * 128; i += 128) {
            int c = i >> 7, t = i & 127;
            Bt[c][t] = src[(b * 64 + c) * 512 + tt0 + t];
        }
        for (int i = tid; i < 64 * 64; i += 128) {
            int c = i >> 6, o = i & 63;
            wT[c][o] = wf[o * 192 + g * 64 + c];
        }
        __syncthreads();
        for (int c = 0; c < 64; ++c) {
            float wv[8], bv[8];
            #pragma unroll
            for (int i = 0; i < 8; ++i) wv[i] = wT[c][o0 + i];
            #pragma unroll
            for (int j = 0; j < 8; ++j) bv[j] = Bt[c][t0 + j];
            #pragma unroll
            for (int i = 0; i < 8; ++i)
                #pragma unroll
                for (int j = 0; j < 8; ++j)
                    acc[i][j] = fmaf(wv[i], bv[j], acc[i][j]);
        }
        __syncthreads();
    }
    #pragma unroll
    for (int i = 0; i < 8; ++i) {
        float bias = bfu[o0 + i];
        #pragma unroll
        for (int j = 0; j < 8; ++j) {
            out[(b * 64 + (o0 + i)) * 512 + tt0 + t0 + j] = gelu_exact(acc[i][j] + bias);
        }
    }
}

extern "C" void kernel_launch(void* const* d_in, const int* in_sizes, int n_in,
                              void* d_out, int out_size, void* d_ws, size_t ws_size,
                              hipStream_t stream) {
    const float* feat = (const float*)d_in[0];
    const float* w0  = (const float*)d_in[1];
    const float* b0  = (const float*)d_in[2];
    const float* w1  = (const float*)d_in[3];
    const float* b1  = (const float*)d_in[4];
    const float* w2  = (const float*)d_in[5];
    const float* b2  = (const float*)d_in[6];
    const float* wpj = (const float*)d_in[7];
    const float* bpj = (const float*)d_in[8];
    const float* wr  = (const float*)d_in[9];
    const float* br  = (const float*)d_in[10];
    const float* wf  = (const float*)d_in[11];
    const float* bfu = (const float*)d_in[12];

    float* ws = (float*)d_ws;
    float* avgb = ws;
    float* maxb = ws + (size_t)NROWS * T_;
    float* seqb = ws + 2 * (size_t)NROWS * T_;

    row_kernel<<<NROWS, 512, 0, stream>>>(feat, w0, b0, w1, b1, w2, b2,
                                          wpj, bpj, wr, br, avgb, maxb, seqb);
    fuse_kernel<<<dim3(4, 32), 128, 0, stream>>>(avgb, maxb, seqb, wf, bfu,
                                                 (float*)d_out);
}

// Round 2
// 319.895 us; speedup vs baseline: 1.2140x; 1.2140x over previous
//
#include <hip/hip_runtime.h>
#include <math.h>

#define B_    32
#define C_    64
#define T_    512
#define NROWS (B_ * C_)
#define CMAX_ 16
#define FEPS  1.1920929e-07f

__device__ __forceinline__ float gelu_exact(float x) {
    return 0.5f * x * (1.0f + erff(x * 0.7071067811865475f));
}

// One block (512 threads) per row r in [0, 2048).
__global__ __launch_bounds__(512) void row_kernel(
    const float* __restrict__ feat,
    const float* __restrict__ w0, const float* __restrict__ b0,
    const float* __restrict__ w1, const float* __restrict__ b1,
    const float* __restrict__ w2, const float* __restrict__ b2,
    const float* __restrict__ wpj, const float* __restrict__ bpj,
    const float* __restrict__ wr, const float* __restrict__ br,
    float* __restrict__ avg_out, float* __restrict__ max_out,
    float* __restrict__ seq_out)
{
    __shared__ __align__(16) float row[T_];
    __shared__ float2 tw[T_];        // cos, sin of 2*pi*i/512
    __shared__ float2 sd[257];       // s[t]=x[t]+x[512-t], d[t]=x[t]-x[512-t]
    __shared__ float rep[512], imp[512];
    __shared__ float amp[257];
    __shared__ float WeffS[3][5][5];
    __shared__ float scal[8];
    __shared__ int   iparam[9];      // P[3], cyc[3], base[3]
    __shared__ float bwv[3];

    const int tid = threadIdx.x;
    const int r = blockIdx.x;

    row[tid] = feat[r * T_ + tid];
    {
        float sv, cv;
        sincosf((float)tid * 0.012271846303085130f, &sv, &cv); // 2*pi/512
        tw[tid] = make_float2(cv, sv);
    }
    if (tid < 75) {
        int k = tid / 25, ij = tid % 25, i = ij / 5, j = ij % 5;
        float w = wpj[2] * w2[k * 25 + i * 5 + j];
        if (i >= 1 && i <= 3 && j >= 1 && j <= 3)
            w += wpj[1] * w1[k * 9 + (i - 1) * 3 + (j - 1)];
        if (i == 2 && j == 2) w += wpj[0] * w0[k];
        WeffS[k][i][j] = w;
    } else if (tid == 80) {
        scal[0] = wpj[0] * b0[0] + wpj[1] * b1[0] + wpj[2] * b2[0] + bpj[0];
        scal[1] = wr[0]; scal[2] = wr[1]; scal[3] = wr[2]; scal[4] = br[0];
    } else if (tid == 81) {
        amp[0] = 0.0f;
    }
    __syncthreads();

    // ---- fold row into symmetric/antisymmetric halves ----
    if (tid >= 1 && tid <= 255) {
        float a = row[tid], b = row[512 - tid];
        sd[tid] = make_float2(a + b, a - b);
    } else if (tid == 256) {
        sd[256] = make_float2(row[256], 0.0f);  // self-paired midpoint
    }
    __syncthreads();

    // ---- half-DFT: 256 freqs x 2 t-half-sums, t = 1..256 ----
    {
        const int f = 1 + (tid & 255);
        const int h = tid >> 8;
        const int tstart = 1 + 128 * h;       // h=0: t=1..128, h=1: t=129..256
        float re = 0.f, im = 0.f;
        int ph = (f * tstart) & 511;
        #pragma unroll 4
        for (int t = tstart; t < tstart + 128; ++t) {
            float2 wv = tw[ph];
            float2 sv = sd[t];                 // lane-uniform broadcast
            re = fmaf(sv.x, wv.x, re);
            im = fmaf(sv.y, wv.y, im);
            ph = (ph + f) & 511;
        }
        rep[tid] = re; imp[tid] = im;
    }
    __syncthreads();
    if (tid < 256) {
        int f1 = tid + 1;
        float re = rep[tid] + rep[tid + 256] + row[0];
        // re gets the x[0] term; x[256] term folded via sd[256]
        float im = imp[tid] + imp[tid + 256];
        amp[f1] = sqrtf(re * re + im * im);
    }
    __syncthreads();

    // ---- wave-parallel top-3 (jax top_k: descending, ties -> lowest idx) ----
    if (tid < 64) {
        float v[5]; int id[5];
        #pragma unroll
        for (int q = 0; q < 4; ++q) { id[q] = tid + 64 * q; v[q] = amp[id[q]]; }
        id[4] = 256; v[4] = (tid == 0) ? amp[256] : -1e30f;
        float vals[3]; int idxs[3];
        #pragma unroll
        for (int kk = 0; kk < 3; ++kk) {
            float bv = v[0]; int bi = id[0];
            #pragma unroll
            for (int q = 1; q < 5; ++q)
                if (v[q] > bv) { bv = v[q]; bi = id[q]; }
            #pragma unroll
            for (int off = 32; off >= 1; off >>= 1) {
                float ov = __shfl_xor(bv, off, 64);
                int   oi = __shfl_xor(bi, off, 64);
                if (ov > bv || (ov == bv && oi < bi)) { bv = ov; bi = oi; }
            }
            vals[kk] = bv; idxs[kk] = bi;
            #pragma unroll
            for (int q = 0; q < 5; ++q)
                if (id[q] == bi) v[q] = -1e30f;
        }
        if (tid == 0) {
            float m = fmaxf(vals[0], fmaxf(vals[1], vals[2]));
            float e0 = expf(vals[0] - m), e1 = expf(vals[1] - m), e2 = expf(vals[2] - m);
            float inv = 1.0f / (e0 + e1 + e2);
            bwv[0] = e0 * inv; bwv[1] = e1 * inv; bwv[2] = e2 * inv;
            #pragma unroll
            for (int kk = 0; kk < 3; ++kk) {
                int fi = idxs[kk] < 1 ? 1 : idxs[kk];
                int P = T_ / fi;
                P = P < 32 ? 32 : (P > 512 ? 512 : P);
                int cyc = T_ / P;
                int bs = T_ - cyc * P;
                iparam[kk] = P; iparam[3 + kk] = cyc; iparam[6 + kk] = bs;
            }
        }
    }
    __syncthreads();

    // ---- fold + conv (row-major sliding accumulate) ----
    const float beff = scal[0], wr0 = scal[1], wr1 = scal[2], wr2 = scal[3], bres = scal[4];
    const int p = tid;

    float zacc[CMAX_];
    #pragma unroll
    for (int i = 0; i < CMAX_; ++i) zacc[i] = beff;

    #pragma unroll
    for (int k = 0; k < 3; ++k) {
        const int P  = __builtin_amdgcn_readfirstlane(iparam[k]);
        const int cy = __builtin_amdgcn_readfirstlane(iparam[3 + k]);
        const int bs = __builtin_amdgcn_readfirstlane(iparam[6 + k]);
        float Wk[5][5];
        #pragma unroll
        for (int i = 0; i < 5; ++i)
            #pragma unroll
            for (int j = 0; j < 5; ++j)
                Wk[i][j] = WeffS[k][i][j];
        bool mdw[5];
        #pragma unroll
        for (int dw = -2; dw <= 2; ++dw)
            mdw[dw + 2] = ((unsigned)(p + dw) < (unsigned)P);
        const int abase = bs + p;
        #pragma unroll
        for (int hh = 0; hh < CMAX_; ++hh) {
            if (hh < cy) {                      // lane-uniform guard
                const int a0 = abase + hh * P;
                float w[5];
                #pragma unroll
                for (int dw = -2; dw <= 2; ++dw) {
                    int a = a0 + dw;
                    a = a < 0 ? 0 : (a > 511 ? 511 : a);
                    w[dw + 2] = mdw[dw + 2] ? row[a] : 0.f;
                }
                #pragma unroll
                for (int dh = -2; dh <= 2; ++dh) {
                    const int cc = hh - dh;     // compile-time
                    if (cc >= 0 && cc < CMAX_) {
                        #pragma unroll
                        for (int dw = 0; dw < 5; ++dw)
                            zacc[cc] = fmaf(Wk[dh + 2][dw], w[dw], zacc[cc]);
                    }
                }
            }
        }
    }

    // ---- residual + gelu + pools ----
    const int P0 = iparam[0], P1 = iparam[1], P2 = iparam[2];
    const int cy0 = iparam[3], cy1 = iparam[4], cy2 = iparam[5];
    const int bs0 = iparam[6], bs1 = iparam[7], bs2 = iparam[8];
    float avg_num = 0.f, den = 0.f, mx = -3.402823466e38f;
    int anyv = 0;
    const int pl0 = (p < P0), pl1 = (p < P1), pl2 = (p < P2);

    #pragma unroll
    for (int cc = 0; cc < CMAX_; ++cc) {
        int m0 = (cc < cy0) & pl0;
        int m1 = (cc < cy1) & pl1;
        int m2 = (cc < cy2) & pl2;
        int a0 = bs0 + cc * P0 + p; a0 = a0 > 511 ? 511 : a0;
        int a1 = bs1 + cc * P1 + p; a1 = a1 > 511 ? 511 : a1;
        int a2 = bs2 + cc * P2 + p; a2 = a2 > 511 ? 511 : a2;
        float x0 = m0 ? row[a0] : 0.f;
        float x1 = m1 ? row[a1] : 0.f;
        float x2 = m2 ? row[a2] : 0.f;
        float res = fmaf(wr0, x0, fmaf(wr1, x1, fmaf(wr2, x2, bres)));
        float z = gelu_exact(zacc[cc]) + res;
        int mm = m0 | m1 | m2;
        float cm = mm ? 1.f : 0.f;
        avg_num += z * cm;
        den += cm;
        mx = mm ? fmaxf(mx, z) : mx;
        anyv |= mm;
    }
    float avg = avg_num / (den + FEPS);
    float mpool = anyv ? mx : 0.f;

    // ---- seq_recon ----
    float seq = 0.f;
    #pragma unroll
    for (int k = 0; k < 3; ++k) {
        const int P  = __builtin_amdgcn_readfirstlane(iparam[k]);
        const int cy = __builtin_amdgcn_readfirstlane(iparam[3 + k]);
        const int bs = __builtin_amdgcn_readfirstlane(iparam[6 + k]);
        float s = 0.f;
        for (int c2 = 0; c2 < cy; ++c2) {
            int a = bs + c2 * P + p; a = a > 511 ? 511 : a;
            s += ((p < P) ? row[a] : 0.f);
        }
        float brk = (p < P) ? s / ((float)cy + FEPS) : 0.f;
        seq = fmaf(bwv[k], brk, seq);
    }

    avg_out[r * T_ + p] = avg;
    max_out[r * T_ + p] = mpool;
    seq_out[r * T_ + p] = seq;
}

// out[b,o,t] = gelu( sum_{c'} wf[o,c'] * comb[b,c',t] + bf[o] )
// grid (8 t-tiles, 32 b), 256 threads, 64o x 64t tile, 4x4 micro-tile.
__global__ __launch_bounds__(256) void fuse_kernel(
    const float* __restrict__ avgb, const float* __restrict__ maxb,
    const float* __restrict__ seqb,
    const float* __restrict__ wf, const float* __restrict__ bfu,
    float* __restrict__ out)
{
    __shared__ float wT[64][68];    // wT[c][o]
    __shared__ float Bt[64][68];    // Bt[c][t]
    const int tid = threadIdx.x;
    const int b = blockIdx.y;
    const int tt0 = blockIdx.x * 64;
    const int og = tid >> 4;        // 0..15
    const int tg = tid & 15;        // 0..15
    const int o0 = og * 4;
    const int t0 = tg * 4;

    float acc[4][4];
    #pragma unroll
    for (int i = 0; i < 4; ++i)
        #pragma unroll
        for (int j = 0; j < 4; ++j) acc[i][j] = 0.f;

    const float* srcs[3] = {avgb, maxb, seqb};
    for (int g = 0; g < 3; ++g) {
        const float* __restrict__ src = srcs[g];
        // 64x64 input tile, float4 loads: 1024 float4s / 256 threads = 4 each
        #pragma unroll
        for (int it = 0; it < 4; ++it) {
            int idx = tid + it * 256;          // 0..1023
            int c = idx >> 4, t4 = idx & 15;
            float4 v = reinterpret_cast<const float4*>(
                           &src[(b * 64 + c) * 512 + tt0])[t4];
            *reinterpret_cast<float4*>(&Bt[c][t4 * 4]) = v;
        }
        for (int i = tid; i < 64 * 64; i += 256) {
            int c = i >> 6, o = i & 63;
            wT[c][o] = wf[o * 192 + g * 64 + c];
        }
        __syncthreads();
        for (int c = 0; c < 64; ++c) {
            float4 wv = reinterpret_cast<const float4*>(&wT[c][0])[og];
            float4 bv = reinterpret_cast<const float4*>(&Bt[c][0])[tg];
            const float wa[4] = {wv.x, wv.y, wv.z, wv.w};
            const float ba[4] = {bv.x, bv.y, bv.z, bv.w};
            #pragma unroll
            for (int i = 0; i < 4; ++i)
                #pragma unroll
                for (int j = 0; j < 4; ++j)
                    acc[i][j] = fmaf(wa[i], ba[j], acc[i][j]);
        }
        __syncthreads();
    }
    #pragma unroll
    for (int i = 0; i < 4; ++i) {
        float bias = bfu[o0 + i];
        float4 o4;
        o4.x = gelu_exact(acc[i][0] + bias);
        o4.y = gelu_exact(acc[i][1] + bias);
        o4.z = gelu_exact(acc[i][2] + bias);
        o4.w = gelu_exact(acc[i][3] + bias);
        *reinterpret_cast<float4*>(
            &out[(b * 64 + (o0 + i)) * 512 + tt0 + t0]) = o4;
    }
}

extern "C" void kernel_launch(void* const* d_in, const int* in_sizes, int n_in,
                              void* d_out, int out_size, void* d_ws, size_t ws_size,
                              hipStream_t stream) {
    const float* feat = (const float*)d_in[0];
    const float* w0  = (const float*)d_in[1];
    const float* b0  = (const float*)d_in[2];
    const float* w1  = (const float*)d_in[3];
    const float* b1  = (const float*)d_in[4];
    const float* w2  = (const float*)d_in[5];
    const float* b2  = (const float*)d_in[6];
    const float* wpj = (const float*)d_in[7];
    const float* bpj = (const float*)d_in[8];
    const float* wr  = (const float*)d_in[9];
    const float* br  = (const float*)d_in[10];
    const float* wf  = (const float*)d_in[11];
    const float* bfu = (const float*)d_in[12];

    float* ws = (float*)d_ws;
    float* avgb = ws;
    float* maxb = ws + (size_t)NROWS * T_;
    float* seqb = ws + 2 * (size_t)NROWS * T_;

    row_kernel<<<NROWS, 512, 0, stream>>>(feat, w0, b0, w1, b1, w2, b2,
                                          wpj, bpj, wr, br, avgb, maxb, seqb);
    fuse_kernel<<<dim3(8, 32), 256, 0, stream>>>(avgb, maxb, seqb, wf, bfu,
                                                 (float*)d_out);
}

// Round 3
// 93.611 us; speedup vs baseline: 4.1487x; 3.4173x over previous
//
#include <hip/hip_runtime.h>
#include <math.h>

#define B_    32
#define C_    64
#define T_    512
#define NROWS (B_ * C_)
#define CMAX_ 16
#define FEPS  1.1920929e-07f

__device__ __forceinline__ float gelu_exact(float x) {
    return 0.5f * x * (1.0f + erff(x * 0.7071067811865475f));
}

// One block (512 threads) per row r in [0, 2048).
__global__ __launch_bounds__(512) void row_kernel(
    const float* __restrict__ feat,
    const float* __restrict__ w0, const float* __restrict__ b0,
    const float* __restrict__ w1, const float* __restrict__ b1,
    const float* __restrict__ w2, const float* __restrict__ b2,
    const float* __restrict__ wpj, const float* __restrict__ bpj,
    const float* __restrict__ wr, const float* __restrict__ br,
    float* __restrict__ avg_out, float* __restrict__ max_out,
    float* __restrict__ seq_out)
{
    __shared__ __align__(16) float row[T_];
    __shared__ float2 tw[T_];        // cos, sin of 2*pi*i/512
    __shared__ float2 sd[257];       // s[t]=x[t]+x[512-t], d[t]=x[t]-x[512-t]
    __shared__ float rep[512], imp[512];
    __shared__ float amp[257];
    __shared__ float WeffS[3][5][5];
    __shared__ float scal[8];
    __shared__ int   iparam[9];      // P[3], cyc[3], base[3]
    __shared__ float bwv[3];

    const int tid = threadIdx.x;
    const int r = blockIdx.x;

    row[tid] = feat[r * T_ + tid];
    {
        float sv, cv;
        sincosf((float)tid * 0.012271846303085130f, &sv, &cv); // 2*pi/512
        tw[tid] = make_float2(cv, sv);
    }
    if (tid < 75) {
        int k = tid / 25, ij = tid % 25, i = ij / 5, j = ij % 5;
        float w = wpj[2] * w2[k * 25 + i * 5 + j];
        if (i >= 1 && i <= 3 && j >= 1 && j <= 3)
            w += wpj[1] * w1[k * 9 + (i - 1) * 3 + (j - 1)];
        if (i == 2 && j == 2) w += wpj[0] * w0[k];
        WeffS[k][i][j] = w;
    } else if (tid == 80) {
        scal[0] = wpj[0] * b0[0] + wpj[1] * b1[0] + wpj[2] * b2[0] + bpj[0];
        scal[1] = wr[0]; scal[2] = wr[1]; scal[3] = wr[2]; scal[4] = br[0];
    } else if (tid == 81) {
        amp[0] = 0.0f;
    }
    __syncthreads();

    // ---- fold row into symmetric/antisymmetric halves ----
    if (tid >= 1 && tid <= 255) {
        float a = row[tid], b = row[512 - tid];
        sd[tid] = make_float2(a + b, a - b);
    } else if (tid == 256) {
        sd[256] = make_float2(row[256], 0.0f);  // self-paired midpoint
    }
    __syncthreads();

    // ---- half-DFT: 256 freqs x 2 t-half-sums, t = 1..256 ----
    {
        const int f = 1 + (tid & 255);
        const int h = tid >> 8;
        const int tstart = 1 + 128 * h;       // h=0: t=1..128, h=1: t=129..256
        float re = 0.f, im = 0.f;
        int ph = (f * tstart) & 511;
        #pragma unroll 4
        for (int t = tstart; t < tstart + 128; ++t) {
            float2 wv = tw[ph];
            float2 sv = sd[t];                 // lane-uniform broadcast
            re = fmaf(sv.x, wv.x, re);
            im = fmaf(sv.y, wv.y, im);
            ph = (ph + f) & 511;
        }
        rep[tid] = re; imp[tid] = im;
    }
    __syncthreads();
    if (tid < 256) {
        int f1 = tid + 1;
        float re = rep[tid] + rep[tid + 256] + row[0];
        float im = imp[tid] + imp[tid + 256];
        amp[f1] = sqrtf(re * re + im * im);
    }
    __syncthreads();

    // ---- wave-parallel top-3 (jax top_k: descending, ties -> lowest idx) ----
    if (tid < 64) {
        float v[5]; int id[5];
        #pragma unroll
        for (int q = 0; q < 4; ++q) { id[q] = tid + 64 * q; v[q] = amp[id[q]]; }
        id[4] = 256; v[4] = (tid == 0) ? amp[256] : -1e30f;
        float vals[3]; int idxs[3];
        #pragma unroll
        for (int kk = 0; kk < 3; ++kk) {
            float bv = v[0]; int bi = id[0];
            #pragma unroll
            for (int q = 1; q < 5; ++q)
                if (v[q] > bv) { bv = v[q]; bi = id[q]; }
            #pragma unroll
            for (int off = 32; off >= 1; off >>= 1) {
                float ov = __shfl_xor(bv, off, 64);
                int   oi = __shfl_xor(bi, off, 64);
                if (ov > bv || (ov == bv && oi < bi)) { bv = ov; bi = oi; }
            }
            vals[kk] = bv; idxs[kk] = bi;
            #pragma unroll
            for (int q = 0; q < 5; ++q)
                if (id[q] == bi) v[q] = -1e30f;
        }
        if (tid == 0) {
            float m = fmaxf(vals[0], fmaxf(vals[1], vals[2]));
            float e0 = expf(vals[0] - m), e1 = expf(vals[1] - m), e2 = expf(vals[2] - m);
            float inv = 1.0f / (e0 + e1 + e2);
            bwv[0] = e0 * inv; bwv[1] = e1 * inv; bwv[2] = e2 * inv;
            #pragma unroll
            for (int kk = 0; kk < 3; ++kk) {
                int fi = idxs[kk] < 1 ? 1 : idxs[kk];
                int P = T_ / fi;
                P = P < 32 ? 32 : (P > 512 ? 512 : P);
                int cyc = T_ / P;
                int bs = T_ - cyc * P;
                iparam[kk] = P; iparam[3 + kk] = cyc; iparam[6 + kk] = bs;
            }
        }
    }
    __syncthreads();
    // ---- no __syncthreads below this line (divergent wave exit is safe) ----

    const float beff = scal[0], wr0 = scal[1], wr1 = scal[2], wr2 = scal[3], bres = scal[4];
    const int p = tid;
    const int wbase = (tid >> 6) << 6;

    const int P0 = iparam[0], P1 = iparam[1], P2 = iparam[2];
    const int cy0 = iparam[3], cy1 = iparam[4], cy2 = iparam[5];
    const int bs0 = iparam[6], bs1 = iparam[7], bs2 = iparam[8];

    int maxP = P0 > P1 ? P0 : P1; maxP = maxP > P2 ? maxP : P2;
    maxP = __builtin_amdgcn_readfirstlane(maxP);
    if (wbase >= maxP) {     // entire wave produces zeros
        avg_out[r * T_ + p] = 0.f;
        max_out[r * T_ + p] = 0.f;
        seq_out[r * T_ + p] = 0.f;
        return;
    }

    // uniform bound on active cycle rows for this wave
    int cymax = 0;
    {
        int c0 = (P0 > wbase) ? cy0 : 0;
        int c1 = (P1 > wbase) ? cy1 : 0;
        int c2 = (P2 > wbase) ? cy2 : 0;
        cymax = c0 > c1 ? c0 : c1; cymax = cymax > c2 ? cymax : c2;
        cymax = __builtin_amdgcn_readfirstlane(cymax);
    }

    // ---- fold + conv (row-major sliding accumulate, one k at a time) ----
    float zacc[CMAX_];
    #pragma unroll
    for (int i = 0; i < CMAX_; ++i) zacc[i] = beff;

    #pragma unroll 1
    for (int k = 0; k < 3; ++k) {
        const int P  = __builtin_amdgcn_readfirstlane(iparam[k]);
        if (wbase >= P) continue;          // wave-uniform skip
        const int cy = __builtin_amdgcn_readfirstlane(iparam[3 + k]);
        const int bs = __builtin_amdgcn_readfirstlane(iparam[6 + k]);
        float Wk[5][5];
        #pragma unroll
        for (int i = 0; i < 5; ++i)
            #pragma unroll
            for (int j = 0; j < 5; ++j)
                Wk[i][j] = WeffS[k][i][j];
        bool mdw[5];
        #pragma unroll
        for (int dw = -2; dw <= 2; ++dw)
            mdw[dw + 2] = ((unsigned)(p + dw) < (unsigned)P);
        const int abase = bs + p;
        #pragma unroll
        for (int hh = 0; hh < CMAX_; ++hh) {
            if (hh < cy) {                 // lane-uniform guard
                const int a0 = abase + hh * P;
                float w[5];
                #pragma unroll
                for (int dw = -2; dw <= 2; ++dw) {
                    int a = a0 + dw;
                    a = a < 0 ? 0 : (a > 511 ? 511 : a);
                    w[dw + 2] = mdw[dw + 2] ? row[a] : 0.f;
                }
                #pragma unroll
                for (int dh = -2; dh <= 2; ++dh) {
                    const int cc = hh - dh;     // compile-time
                    if (cc >= 0 && cc < CMAX_) {
                        #pragma unroll
                        for (int dw = 0; dw < 5; ++dw)
                            zacc[cc] = fmaf(Wk[dh + 2][dw], w[dw], zacc[cc]);
                    }
                }
            }
        }
    }

    // ---- residual + gelu + pools (only cc < cymax can be active) ----
    float avg_num = 0.f, den = 0.f, mx = -3.402823466e38f;
    int anyv = 0;
    const int pl0 = (p < P0), pl1 = (p < P1), pl2 = (p < P2);

    #pragma unroll
    for (int cc = 0; cc < CMAX_; ++cc) {
        if (cc < cymax) {                  // uniform guard
            int m0 = (cc < cy0) & pl0;
            int m1 = (cc < cy1) & pl1;
            int m2 = (cc < cy2) & pl2;
            int a0 = bs0 + cc * P0 + p; a0 = a0 > 511 ? 511 : a0;
            int a1 = bs1 + cc * P1 + p; a1 = a1 > 511 ? 511 : a1;
            int a2 = bs2 + cc * P2 + p; a2 = a2 > 511 ? 511 : a2;
            float x0 = m0 ? row[a0] : 0.f;
            float x1 = m1 ? row[a1] : 0.f;
            float x2 = m2 ? row[a2] : 0.f;
            float res = fmaf(wr0, x0, fmaf(wr1, x1, fmaf(wr2, x2, bres)));
            float z = gelu_exact(zacc[cc]) + res;
            int mm = m0 | m1 | m2;
            float cm = mm ? 1.f : 0.f;
            avg_num += z * cm;
            den += cm;
            mx = mm ? fmaxf(mx, z) : mx;
            anyv |= mm;
        }
    }
    float avg = avg_num / (den + FEPS);
    float mpool = anyv ? mx : 0.f;

    // ---- seq_recon ----
    float seq = 0.f;
    #pragma unroll 1
    for (int k = 0; k < 3; ++k) {
        const int P  = __builtin_amdgcn_readfirstlane(iparam[k]);
        if (wbase >= P) continue;
        const int cy = __builtin_amdgcn_readfirstlane(iparam[3 + k]);
        const int bs = __builtin_amdgcn_readfirstlane(iparam[6 + k]);
        float s = 0.f;
        for (int c2 = 0; c2 < cy; ++c2) {
            int a = bs + c2 * P + p; a = a > 511 ? 511 : a;
            s += ((p < P) ? row[a] : 0.f);
        }
        float brk = (p < P) ? s / ((float)cy + FEPS) : 0.f;
        seq = fmaf(bwv[k], brk, seq);
    }

    avg_out[r * T_ + p] = avg;
    max_out[r * T_ + p] = mpool;
    seq_out[r * T_ + p] = seq;
}

// out[b,o,t] = gelu( sum_{c'} wf[o,c'] * comb[b,c',t] + bf[o] )
// grid (8 t-tiles, 32 b), 256 threads, 64o x 64t tile, 4x4 micro-tile.
__global__ __launch_bounds__(256) void fuse_kernel(
    const float* __restrict__ avgb, const float* __restrict__ maxb,
    const float* __restrict__ seqb,
    const float* __restrict__ wf, const float* __restrict__ bfu,
    float* __restrict__ out)
{
    __shared__ float wT[64][68];    // wT[c][o]
    __shared__ float Bt[64][68];    // Bt[c][t]
    const int tid = threadIdx.x;
    const int b = blockIdx.y;
    const int tt0 = blockIdx.x * 64;
    const int og = tid >> 4;        // 0..15
    const int tg = tid & 15;        // 0..15
    const int o0 = og * 4;
    const int t0 = tg * 4;

    float acc[4][4];
    #pragma unroll
    for (int i = 0; i < 4; ++i)
        #pragma unroll
        for (int j = 0; j < 4; ++j) acc[i][j] = 0.f;

    const float* srcs[3] = {avgb, maxb, seqb};
    for (int g = 0; g < 3; ++g) {
        const float* __restrict__ src = srcs[g];
        #pragma unroll
        for (int it = 0; it < 4; ++it) {
            int idx = tid + it * 256;          // 0..1023
            int c = idx >> 4, t4 = idx & 15;
            float4 v = reinterpret_cast<const float4*>(
                           &src[(b * 64 + c) * 512 + tt0])[t4];
            *reinterpret_cast<float4*>(&Bt[c][t4 * 4]) = v;
        }
        for (int i = tid; i < 64 * 64; i += 256) {
            int c = i >> 6, o = i & 63;
            wT[c][o] = wf[o * 192 + g * 64 + c];
        }
        __syncthreads();
        for (int c = 0; c < 64; ++c) {
            float4 wv = reinterpret_cast<const float4*>(&wT[c][0])[og];
            float4 bv = reinterpret_cast<const float4*>(&Bt[c][0])[tg];
            const float wa[4] = {wv.x, wv.y, wv.z, wv.w};
            const float ba[4] = {bv.x, bv.y, bv.z, bv.w};
            #pragma unroll
            for (int i = 0; i < 4; ++i)
                #pragma unroll
                for (int j = 0; j < 4; ++j)
                    acc[i][j] = fmaf(wa[i], ba[j], acc[i][j]);
        }
        __syncthreads();
    }
    #pragma unroll
    for (int i = 0; i < 4; ++i) {
        float bias = bfu[o0 + i];
        float4 o4;
        o4.x = gelu_exact(acc[i][0] + bias);
        o4.y = gelu_exact(acc[i][1] + bias);
        o4.z = gelu_exact(acc[i][2] + bias);
        o4.w = gelu_exact(acc[i][3] + bias);
        *reinterpret_cast<float4*>(
            &out[(b * 64 + (o0 + i)) * 512 + tt0 + t0]) = o4;
    }
}

extern "C" void kernel_launch(void* const* d_in, const int* in_sizes, int n_in,
                              void* d_out, int out_size, void* d_ws, size_t ws_size,
                              hipStream_t stream) {
    const float* feat = (const float*)d_in[0];
    const float* w0  = (const float*)d_in[1];
    const float* b0  = (const float*)d_in[2];
    const float* w1  = (const float*)d_in[3];
    const float* b1  = (const float*)d_in[4];
    const float* w2  = (const float*)d_in[5];
    const float* b2  = (const float*)d_in[6];
    const float* wpj = (const float*)d_in[7];
    const float* bpj = (const float*)d_in[8];
    const float* wr  = (const float*)d_in[9];
    const float* br  = (const float*)d_in[10];
    const float* wf  = (const float*)d_in[11];
    const float* bfu = (const float*)d_in[12];

    float* ws = (float*)d_ws;
    float* avgb = ws;
    float* maxb = ws + (size_t)NROWS * T_;
    float* seqb = ws + 2 * (size_t)NROWS * T_;

    row_kernel<<<NROWS, 512, 0, stream>>>(feat, w0, b0, w1, b1, w2, b2,
                                          wpj, bpj, wr, br, avgb, maxb, seqb);
    fuse_kernel<<<dim3(8, 32), 256, 0, stream>>>(avgb, maxb, seqb, wf, bfu,
                                                 (float*)d_out);
}

// Round 4
// 83.869 us; speedup vs baseline: 4.6306x; 1.1162x over previous
//
#include <hip/hip_runtime.h>
#include <math.h>

#define B_    32
#define C_    64
#define T_    512
#define NROWS (B_ * C_)
#define CMAX_ 16
#define FEPS  1.1920929e-07f
#define W2PI  0.012271846303085130f   // 2*pi/512

__device__ __forceinline__ float gelu_exact(float x) {
    return 0.5f * x * (1.0f + erff(x * 0.7071067811865475f));
}

// ---------- kernel 0: fold conv weights into one 5x5x3 kernel + scalars ----
// wc[0..74]  = Weff[k][i][j]  (flat k*25+i*5+j)
// wc[75]     = beff, wc[76..78] = wr[0..2], wc[79] = br
__global__ void prep_kernel(
    const float* __restrict__ w0, const float* __restrict__ b0,
    const float* __restrict__ w1, const float* __restrict__ b1,
    const float* __restrict__ w2, const float* __restrict__ b2,
    const float* __restrict__ wpj, const float* __restrict__ bpj,
    const float* __restrict__ wr, const float* __restrict__ br,
    float* __restrict__ wc)
{
    const int tid = threadIdx.x;
    if (tid < 75) {
        int k = tid / 25, ij = tid % 25, i = ij / 5, j = ij % 5;
        float w = wpj[2] * w2[k * 25 + i * 5 + j];
        if (i >= 1 && i <= 3 && j >= 1 && j <= 3)
            w += wpj[1] * w1[k * 9 + (i - 1) * 3 + (j - 1)];
        if (i == 2 && j == 2) w += wpj[0] * w0[k];
        wc[tid] = w;
    } else if (tid == 75) {
        wc[75] = wpj[0] * b0[0] + wpj[1] * b1[0] + wpj[2] * b2[0] + bpj[0];
    } else if (tid <= 78) {
        wc[tid] = wr[tid - 76];
    } else if (tid == 79) {
        wc[79] = br[0];
    }
}

// ---------- kernel 1: DFT amplitudes + top-3 -> per-row params ----------
// params[r*16 + 0..2] = P (as int bits), 3..5 = cyc, 6..8 = base, 9..11 = bw
__global__ __launch_bounds__(512) void dft_kernel(
    const float* __restrict__ feat, float* __restrict__ params)
{
    __shared__ __align__(16) float row[T_];
    __shared__ float2 sd[257];       // s[t]=x[t]+x[512-t], d[t]=x[t]-x[512-t]
    __shared__ float rep[512], imp[512];
    __shared__ float amp[257];

    const int tid = threadIdx.x;
    const int r = blockIdx.x;

    row[tid] = feat[r * T_ + tid];
    if (tid == 0) amp[0] = 0.0f;
    __syncthreads();

    if (tid >= 1 && tid <= 255) {
        float a = row[tid], b = row[512 - tid];
        sd[tid] = make_float2(a + b, a - b);
    } else if (tid == 256) {
        sd[256] = make_float2(row[256], 0.0f);
    }
    __syncthreads();

    // half-DFT via in-register rotation recurrence (no twiddle table)
    {
        const int f = 1 + (tid & 255);
        const int tstart = 1 + 128 * (tid >> 8);
        float cF, sF;
        sincosf((float)f * W2PI, &sF, &cF);
        const int ph0 = (f * tstart) & 511;
        float c, s;
        sincosf((float)ph0 * W2PI, &s, &c);
        float re = 0.f, im = 0.f;
        #pragma unroll 4
        for (int t = tstart; t < tstart + 128; ++t) {
            float2 v = sd[t];              // wave-uniform broadcast
            re = fmaf(v.x, c, re);
            im = fmaf(v.y, s, im);
            float cn = fmaf(-s, sF, c * cF);
            float sn = fmaf( c, sF, s * cF);
            c = cn; s = sn;
        }
        rep[tid] = re; imp[tid] = im;
    }
    __syncthreads();
    if (tid < 256) {
        float re = rep[tid] + rep[tid + 256] + row[0];
        float im = imp[tid] + imp[tid + 256];
        amp[tid + 1] = sqrtf(re * re + im * im);
    }
    __syncthreads();

    // wave-parallel top-3 (jax top_k: descending, ties -> lowest idx)
    if (tid < 64) {
        float v[5]; int id[5];
        #pragma unroll
        for (int q = 0; q < 4; ++q) { id[q] = tid + 64 * q; v[q] = amp[id[q]]; }
        id[4] = 256; v[4] = (tid == 0) ? amp[256] : -1e30f;
        float vals[3]; int idxs[3];
        #pragma unroll
        for (int kk = 0; kk < 3; ++kk) {
            float bv = v[0]; int bi = id[0];
            #pragma unroll
            for (int q = 1; q < 5; ++q)
                if (v[q] > bv) { bv = v[q]; bi = id[q]; }
            #pragma unroll
            for (int off = 32; off >= 1; off >>= 1) {
                float ov = __shfl_xor(bv, off, 64);
                int   oi = __shfl_xor(bi, off, 64);
                if (ov > bv || (ov == bv && oi < bi)) { bv = ov; bi = oi; }
            }
            vals[kk] = bv; idxs[kk] = bi;
            #pragma unroll
            for (int q = 0; q < 5; ++q)
                if (id[q] == bi) v[q] = -1e30f;
        }
        if (tid == 0) {
            float m = fmaxf(vals[0], fmaxf(vals[1], vals[2]));
            float e0 = expf(vals[0] - m), e1 = expf(vals[1] - m), e2 = expf(vals[2] - m);
            float inv = 1.0f / (e0 + e1 + e2);
            float* pr = params + r * 16;
            #pragma unroll
            for (int kk = 0; kk < 3; ++kk) {
                int fi = idxs[kk] < 1 ? 1 : idxs[kk];
                int P = T_ / fi;
                P = P < 32 ? 32 : (P > 512 ? 512 : P);
                int cyc = T_ / P;
                int bs = T_ - cyc * P;
                pr[kk]     = __int_as_float(P);
                pr[3 + kk] = __int_as_float(cyc);
                pr[6 + kk] = __int_as_float(bs);
            }
            pr[9]  = e0 * inv;
            pr[10] = e1 * inv;
            pr[11] = e2 * inv;
        }
    }
}

// ---------- kernel 2: fold + conv + gelu + pools + seq_recon ----------
// one 64-thread block per row; loops p in chunks of 64.
__global__ __launch_bounds__(64) void fold_kernel(
    const float* __restrict__ feat, const float* __restrict__ params,
    const float* __restrict__ wc,
    float* __restrict__ avg_out, float* __restrict__ max_out,
    float* __restrict__ seq_out)
{
    __shared__ __align__(16) float row[T_];
    __shared__ float WeffS[80];

    const int tid = threadIdx.x;
    const int r = blockIdx.x;

    {
        const float4* f4 = reinterpret_cast<const float4*>(feat + (size_t)r * T_);
        float4* r4 = reinterpret_cast<float4*>(row);
        r4[tid] = f4[tid];
        r4[tid + 64] = f4[tid + 64];
    }
    for (int i = tid; i < 80; i += 64) WeffS[i] = wc[i];
    __syncthreads();

    const float* pr = params + r * 16;
    const int P0  = __builtin_amdgcn_readfirstlane(__float_as_int(pr[0]));
    const int P1  = __builtin_amdgcn_readfirstlane(__float_as_int(pr[1]));
    const int P2  = __builtin_amdgcn_readfirstlane(__float_as_int(pr[2]));
    const int cy0 = __builtin_amdgcn_readfirstlane(__float_as_int(pr[3]));
    const int cy1 = __builtin_amdgcn_readfirstlane(__float_as_int(pr[4]));
    const int cy2 = __builtin_amdgcn_readfirstlane(__float_as_int(pr[5]));
    const int bs0 = __builtin_amdgcn_readfirstlane(__float_as_int(pr[6]));
    const int bs1 = __builtin_amdgcn_readfirstlane(__float_as_int(pr[7]));
    const int bs2 = __builtin_amdgcn_readfirstlane(__float_as_int(pr[8]));
    const float bw0 = pr[9], bw1 = pr[10], bw2 = pr[11];
    const float beff = WeffS[75], wr0 = WeffS[76], wr1 = WeffS[77],
                wr2 = WeffS[78], bres = WeffS[79];

    int maxP = P0 > P1 ? P0 : P1; maxP = maxP > P2 ? maxP : P2;

    const int Pk[3]  = {P0, P1, P2};
    const int cykA[3] = {cy0, cy1, cy2};
    const int bskA[3] = {bs0, bs1, bs2};

    #pragma unroll 1
    for (int pc = 0; pc < T_; pc += 64) {
        const int p = pc + tid;
        if (pc >= maxP) {
            avg_out[r * T_ + p] = 0.f;
            max_out[r * T_ + p] = 0.f;
            seq_out[r * T_ + p] = 0.f;
            continue;
        }
        // uniform bound on active cycle rows for this chunk
        int c0 = (P0 > pc) ? cy0 : 0;
        int c1 = (P1 > pc) ? cy1 : 0;
        int c2 = (P2 > pc) ? cy2 : 0;
        int cymax = c0 > c1 ? c0 : c1; cymax = cymax > c2 ? cymax : c2;

        float zacc[CMAX_];
        #pragma unroll
        for (int i = 0; i < CMAX_; ++i) zacc[i] = beff;

        #pragma unroll 1
        for (int k = 0; k < 3; ++k) {
            const int P = Pk[k];
            if (pc >= P) continue;          // wave-uniform skip
            const int cy = cykA[k];
            const int bs = bskA[k];
            float Wk[5][5];
            #pragma unroll
            for (int i = 0; i < 5; ++i)
                #pragma unroll
                for (int j = 0; j < 5; ++j)
                    Wk[i][j] = WeffS[k * 25 + i * 5 + j];
            bool mdw[5];
            #pragma unroll
            for (int dw = -2; dw <= 2; ++dw)
                mdw[dw + 2] = ((unsigned)(p + dw) < (unsigned)P);
            const int abase = bs + p;
            #pragma unroll
            for (int hh = 0; hh < CMAX_; ++hh) {
                if (hh < cy) {              // lane-uniform guard
                    const int a0 = abase + hh * P;
                    float w[5];
                    #pragma unroll
                    for (int dw = -2; dw <= 2; ++dw) {
                        int a = a0 + dw;
                        a = a < 0 ? 0 : (a > 511 ? 511 : a);
                        w[dw + 2] = mdw[dw + 2] ? row[a] : 0.f;
                    }
                    #pragma unroll
                    for (int dh = -2; dh <= 2; ++dh) {
                        const int cc = hh - dh;   // compile-time
                        if (cc >= 0 && cc < CMAX_) {
                            #pragma unroll
                            for (int dw = 0; dw < 5; ++dw)
                                zacc[cc] = fmaf(Wk[dh + 2][dw], w[dw], zacc[cc]);
                        }
                    }
                }
            }
        }

        // residual + gelu + pools
        float avg_num = 0.f, den = 0.f, mx = -3.402823466e38f;
        int anyv = 0;
        const int pl0 = (p < P0), pl1 = (p < P1), pl2 = (p < P2);
        #pragma unroll
        for (int cc = 0; cc < CMAX_; ++cc) {
            if (cc < cymax) {               // uniform guard
                int m0 = (cc < cy0) & pl0;
                int m1 = (cc < cy1) & pl1;
                int m2 = (cc < cy2) & pl2;
                int a0 = bs0 + cc * P0 + p; a0 = a0 > 511 ? 511 : a0;
                int a1 = bs1 + cc * P1 + p; a1 = a1 > 511 ? 511 : a1;
                int a2 = bs2 + cc * P2 + p; a2 = a2 > 511 ? 511 : a2;
                float x0 = m0 ? row[a0] : 0.f;
                float x1 = m1 ? row[a1] : 0.f;
                float x2 = m2 ? row[a2] : 0.f;
                float res = fmaf(wr0, x0, fmaf(wr1, x1, fmaf(wr2, x2, bres)));
                float z = gelu_exact(zacc[cc]) + res;
                int mm = m0 | m1 | m2;
                float cm = mm ? 1.f : 0.f;
                avg_num += z * cm;
                den += cm;
                mx = mm ? fmaxf(mx, z) : mx;
                anyv |= mm;
            }
        }
        float avg = avg_num / (den + FEPS);
        float mpool = anyv ? mx : 0.f;

        // seq_recon
        float seq = 0.f;
        #pragma unroll 1
        for (int k = 0; k < 3; ++k) {
            const int P = Pk[k];
            if (pc >= P) continue;
            const int cy = cykA[k];
            const int bs = bskA[k];
            float s = 0.f;
            for (int c2i = 0; c2i < cy; ++c2i) {
                int a = bs + c2i * P + p; a = a > 511 ? 511 : a;
                s += ((p < P) ? row[a] : 0.f);
            }
            float brk = (p < P) ? s / ((float)cy + FEPS) : 0.f;
            float bwk = (k == 0) ? bw0 : (k == 1 ? bw1 : bw2);
            seq = fmaf(bwk, brk, seq);
        }

        avg_out[r * T_ + p] = avg;
        max_out[r * T_ + p] = mpool;
        seq_out[r * T_ + p] = seq;
    }
}

// ---------- kernel 3: fuse GEMM + gelu ----------
__global__ __launch_bounds__(256) void fuse_kernel(
    const float* __restrict__ avgb, const float* __restrict__ maxb,
    const float* __restrict__ seqb,
    const float* __restrict__ wf, const float* __restrict__ bfu,
    float* __restrict__ out)
{
    __shared__ float wT[64][68];    // wT[c][o]
    __shared__ float Bt[64][68];    // Bt[c][t]
    const int tid = threadIdx.x;
    const int b = blockIdx.y;
    const int tt0 = blockIdx.x * 64;
    const int og = tid >> 4;
    const int tg = tid & 15;
    const int o0 = og * 4;
    const int t0 = tg * 4;

    float acc[4][4];
    #pragma unroll
    for (int i = 0; i < 4; ++i)
        #pragma unroll
        for (int j = 0; j < 4; ++j) acc[i][j] = 0.f;

    const float* srcs[3] = {avgb, maxb, seqb};
    for (int g = 0; g < 3; ++g) {
        const float* __restrict__ src = srcs[g];
        #pragma unroll
        for (int it = 0; it < 4; ++it) {
            int idx = tid + it * 256;
            int c = idx >> 4, t4 = idx & 15;
            float4 v = reinterpret_cast<const float4*>(
                           &src[(b * 64 + c) * 512 + tt0])[t4];
            *reinterpret_cast<float4*>(&Bt[c][t4 * 4]) = v;
        }
        for (int i = tid; i < 64 * 64; i += 256) {
            int c = i >> 6, o = i & 63;
            wT[c][o] = wf[o * 192 + g * 64 + c];
        }
        __syncthreads();
        for (int c = 0; c < 64; ++c) {
            float4 wv = reinterpret_cast<const float4*>(&wT[c][0])[og];
            float4 bv = reinterpret_cast<const float4*>(&Bt[c][0])[tg];
            const float wa[4] = {wv.x, wv.y, wv.z, wv.w};
            const float ba[4] = {bv.x, bv.y, bv.z, bv.w};
            #pragma unroll
            for (int i = 0; i < 4; ++i)
                #pragma unroll
                for (int j = 0; j < 4; ++j)
                    acc[i][j] = fmaf(wa[i], ba[j], acc[i][j]);
        }
        __syncthreads();
    }
    #pragma unroll
    for (int i = 0; i < 4; ++i) {
        float bias = bfu[o0 + i];
        float4 o4;
        o4.x = gelu_exact(acc[i][0] + bias);
        o4.y = gelu_exact(acc[i][1] + bias);
        o4.z = gelu_exact(acc[i][2] + bias);
        o4.w = gelu_exact(acc[i][3] + bias);
        *reinterpret_cast<float4*>(
            &out[(b * 64 + (o0 + i)) * 512 + tt0 + t0]) = o4;
    }
}

extern "C" void kernel_launch(void* const* d_in, const int* in_sizes, int n_in,
                              void* d_out, int out_size, void* d_ws, size_t ws_size,
                              hipStream_t stream) {
    const float* feat = (const float*)d_in[0];
    const float* w0  = (const float*)d_in[1];
    const float* b0  = (const float*)d_in[2];
    const float* w1  = (const float*)d_in[3];
    const float* b1  = (const float*)d_in[4];
    const float* w2  = (const float*)d_in[5];
    const float* b2  = (const float*)d_in[6];
    const float* wpj = (const float*)d_in[7];
    const float* bpj = (const float*)d_in[8];
    const float* wr  = (const float*)d_in[9];
    const float* br  = (const float*)d_in[10];
    const float* wf  = (const float*)d_in[11];
    const float* bfu = (const float*)d_in[12];

    float* ws = (float*)d_ws;
    float* avgb   = ws;
    float* maxb   = ws + (size_t)NROWS * T_;
    float* seqb   = ws + 2 * (size_t)NROWS * T_;
    float* params = ws + 3 * (size_t)NROWS * T_;
    float* wc     = params + (size_t)NROWS * 16;

    prep_kernel<<<1, 80, 0, stream>>>(w0, b0, w1, b1, w2, b2, wpj, bpj, wr, br, wc);
    dft_kernel<<<NROWS, 512, 0, stream>>>(feat, params);
    fold_kernel<<<NROWS, 64, 0, stream>>>(feat, params, wc, avgb, maxb, seqb);
    fuse_kernel<<<dim3(8, 32), 256, 0, stream>>>(avgb, maxb, seqb, wf, bfu,
                                                 (float*)d_out);
}

// Round 6
// 73.106 us; speedup vs baseline: 5.3123x; 1.1472x over previous
//
#include <hip/hip_runtime.h>
#include <math.h>

#define B_    32
#define C_    64
#define T_    512
#define NROWS (B_ * C_)
#define CMAX_ 16
#define FEPS  1.1920929e-07f
#define W2PI  0.012271846303085130f   // 2*pi/512

__device__ __forceinline__ float gelu_exact(float x) {
    return 0.5f * x * (1.0f + erff(x * 0.7071067811865475f));
}

// ---------- kernel 1: DFT amplitudes + top-3 -> per-row params ----------
// One 64-thread wave per row. Each thread owns 4 freqs f = 1+tid+64q.
// params[r*16 + 0..2] = P (int bits), 3..5 = cyc, 6..8 = base, 9..11 = bw
__global__ __launch_bounds__(64) void dft_kernel(
    const float* __restrict__ feat, float* __restrict__ params)
{
    __shared__ __align__(16) float row[T_];
    __shared__ __align__(16) float2 sds[256];   // sds[i] = (s,d) for t=i+1

    const int tid = threadIdx.x;
    const int r = blockIdx.x;

    {
        const float4* f4 = reinterpret_cast<const float4*>(feat + (size_t)r * T_);
        float4* r4 = reinterpret_cast<float4*>(row);
        r4[tid] = f4[tid];                 // 128 float4 total = 512 floats
        r4[tid + 64] = f4[tid + 64];
    }
    __syncthreads();

    // s[t]=x[t]+x[512-t], d[t]=x[t]-x[512-t], t=1..255; t=256 self-paired
    for (int i = tid; i < 255; i += 64) {
        float a = row[i + 1], b = row[511 - i];
        sds[i] = make_float2(a + b, a - b);
    }
    if (tid == 0) sds[255] = make_float2(row[256], 0.0f);
    __syncthreads();

    // 4 freqs/thread, 4 rotation chains per freq, float4 sd reads
    float chc[4][4], chs[4][4], cS[4], sS[4], re[4], im[4];
    #pragma unroll
    for (int q = 0; q < 4; ++q) {
        const int fq = 1 + tid + 64 * q;
        const int a4 = (4 * fq) & 511;
        sincosf((float)a4 * W2PI, &sS[q], &cS[q]);
        #pragma unroll
        for (int j = 0; j < 4; ++j) {
            const int ph = (fq * (1 + j)) & 511;
            sincosf((float)ph * W2PI, &chs[q][j], &chc[q][j]);
        }
        re[q] = 0.f; im[q] = 0.f;
    }

    const float4* s4 = reinterpret_cast<const float4*>(sds);
    #pragma unroll 2
    for (int g = 0; g < 64; ++g) {
        const float4 q0 = s4[2 * g];
        const float4 q1 = s4[2 * g + 1];
        const float ex[4] = {q0.x, q0.z, q1.x, q1.z};
        const float ey[4] = {q0.y, q0.w, q1.y, q1.w};
        #pragma unroll
        for (int q = 0; q < 4; ++q) {
            #pragma unroll
            for (int j = 0; j < 4; ++j) {
                re[q] = fmaf(ex[j], chc[q][j], re[q]);
                im[q] = fmaf(ey[j], chs[q][j], im[q]);
                float cn = fmaf(-chs[q][j], sS[q], chc[q][j] * cS[q]);
                float sn = fmaf( chc[q][j], sS[q], chs[q][j] * cS[q]);
                chc[q][j] = cn; chs[q][j] = sn;
            }
        }
    }

    const float x0 = row[0];
    float v[4]; int id[4];
    #pragma unroll
    for (int q = 0; q < 4; ++q) {
        float rr = re[q] + x0;
        v[q] = sqrtf(rr * rr + im[q] * im[q]);
        id[q] = 1 + tid + 64 * q;
    }

    // wave top-3 (jax top_k: descending, ties -> lowest idx)
    float vals[3]; int idxs[3];
    #pragma unroll
    for (int kk = 0; kk < 3; ++kk) {
        float bv = v[0]; int bi = id[0];
        #pragma unroll
        for (int q = 1; q < 4; ++q)
            if (v[q] > bv) { bv = v[q]; bi = id[q]; }
        #pragma unroll
        for (int off = 32; off >= 1; off >>= 1) {
            float ov = __shfl_xor(bv, off, 64);
            int   oi = __shfl_xor(bi, off, 64);
            if (ov > bv || (ov == bv && oi < bi)) { bv = ov; bi = oi; }
        }
        vals[kk] = bv; idxs[kk] = bi;
        #pragma unroll
        for (int q = 0; q < 4; ++q)
            if (id[q] == bi) v[q] = -1e30f;
    }
    if (tid == 0) {
        float m = fmaxf(vals[0], fmaxf(vals[1], vals[2]));
        float e0 = expf(vals[0] - m), e1 = expf(vals[1] - m), e2 = expf(vals[2] - m);
        float inv = 1.0f / (e0 + e1 + e2);
        float* pr = params + r * 16;
        #pragma unroll
        for (int kk = 0; kk < 3; ++kk) {
            int fi = idxs[kk];
            int P = T_ / fi;
            P = P < 32 ? 32 : (P > 512 ? 512 : P);
            int cyc = T_ / P;
            int bs = T_ - cyc * P;
            pr[kk]     = __int_as_float(P);
            pr[3 + kk] = __int_as_float(cyc);
            pr[6 + kk] = __int_as_float(bs);
        }
        pr[9]  = e0 * inv;
        pr[10] = e1 * inv;
        pr[11] = e2 * inv;
    }
}

// ---------- kernel 2: fold + conv + gelu + pools + seq_recon ----------
// one 64-thread block per row; loops p in chunks of 64.
__global__ __launch_bounds__(64) void fold_kernel(
    const float* __restrict__ feat, const float* __restrict__ params,
    const float* __restrict__ w0, const float* __restrict__ b0,
    const float* __restrict__ w1, const float* __restrict__ b1,
    const float* __restrict__ w2, const float* __restrict__ b2,
    const float* __restrict__ wpj, const float* __restrict__ bpj,
    const float* __restrict__ wr, const float* __restrict__ br,
    float* __restrict__ avg_out, float* __restrict__ max_out,
    float* __restrict__ seq_out)
{
    __shared__ __align__(16) float row[T_];
    __shared__ float WeffS[80];

    const int tid = threadIdx.x;
    const int r = blockIdx.x;

    {
        const float4* f4 = reinterpret_cast<const float4*>(feat + (size_t)r * T_);
        float4* r4 = reinterpret_cast<float4*>(row);
        r4[tid] = f4[tid];
        r4[tid + 64] = f4[tid + 64];
    }
    for (int i = tid; i < 80; i += 64) {
        if (i < 75) {
            int k = i / 25, ij = i % 25, ii = ij / 5, jj = ij % 5;
            float w = wpj[2] * w2[k * 25 + ii * 5 + jj];
            if (ii >= 1 && ii <= 3 && jj >= 1 && jj <= 3)
                w += wpj[1] * w1[k * 9 + (ii - 1) * 3 + (jj - 1)];
            if (ii == 2 && jj == 2) w += wpj[0] * w0[k];
            WeffS[i] = w;
        } else if (i == 75) {
            WeffS[75] = wpj[0] * b0[0] + wpj[1] * b1[0] + wpj[2] * b2[0] + bpj[0];
        } else if (i <= 78) {
            WeffS[i] = wr[i - 76];
        } else {
            WeffS[79] = br[0];
        }
    }
    __syncthreads();

    const float* pr = params + r * 16;
    const int P0  = __builtin_amdgcn_readfirstlane(__float_as_int(pr[0]));
    const int P1  = __builtin_amdgcn_readfirstlane(__float_as_int(pr[1]));
    const int P2  = __builtin_amdgcn_readfirstlane(__float_as_int(pr[2]));
    const int cy0 = __builtin_amdgcn_readfirstlane(__float_as_int(pr[3]));
    const int cy1 = __builtin_amdgcn_readfirstlane(__float_as_int(pr[4]));
    const int cy2 = __builtin_amdgcn_readfirstlane(__float_as_int(pr[5]));
    const int bs0 = __builtin_amdgcn_readfirstlane(__float_as_int(pr[6]));
    const int bs1 = __builtin_amdgcn_readfirstlane(__float_as_int(pr[7]));
    const int bs2 = __builtin_amdgcn_readfirstlane(__float_as_int(pr[8]));
    const float bw0 = pr[9], bw1 = pr[10], bw2 = pr[11];
    const float beff = WeffS[75], wr0 = WeffS[76], wr1 = WeffS[77],
                wr2 = WeffS[78], bres = WeffS[79];

    int maxP = P0 > P1 ? P0 : P1; maxP = maxP > P2 ? maxP : P2;

    const int Pk[3]   = {P0, P1, P2};
    const int cykA[3] = {cy0, cy1, cy2};
    const int bskA[3] = {bs0, bs1, bs2};

    #pragma unroll 1
    for (int pc = 0; pc < T_; pc += 64) {
        const int p = pc + tid;
        if (pc >= maxP) {
            avg_out[r * T_ + p] = 0.f;
            max_out[r * T_ + p] = 0.f;
            seq_out[r * T_ + p] = 0.f;
            continue;
        }
        int c0 = (P0 > pc) ? cy0 : 0;
        int c1 = (P1 > pc) ? cy1 : 0;
        int c2 = (P2 > pc) ? cy2 : 0;
        int cymax = c0 > c1 ? c0 : c1; cymax = cymax > c2 ? cymax : c2;

        float zacc[CMAX_];
        #pragma unroll
        for (int i = 0; i < CMAX_; ++i) zacc[i] = beff;

        #pragma unroll 1
        for (int k = 0; k < 3; ++k) {
            const int P = Pk[k];
            if (pc >= P) continue;          // wave-uniform skip
            const int cy = cykA[k];
            const int bs = bskA[k];
            float Wk[5][5];
            #pragma unroll
            for (int i = 0; i < 5; ++i)
                #pragma unroll
                for (int j = 0; j < 5; ++j)
                    Wk[i][j] = WeffS[k * 25 + i * 5 + j];
            bool mdw[5];
            #pragma unroll
            for (int dw = -2; dw <= 2; ++dw)
                mdw[dw + 2] = ((unsigned)(p + dw) < (unsigned)P);
            const int abase = bs + p;
            #pragma unroll
            for (int hh = 0; hh < CMAX_; ++hh) {
                if (hh < cy) {              // lane-uniform guard
                    const int a0 = abase + hh * P;
                    float w[5];
                    #pragma unroll
                    for (int dw = -2; dw <= 2; ++dw) {
                        int a = a0 + dw;
                        a = a < 0 ? 0 : (a > 511 ? 511 : a);
                        w[dw + 2] = mdw[dw + 2] ? row[a] : 0.f;
                    }
                    #pragma unroll
                    for (int dh = -2; dh <= 2; ++dh) {
                        const int cc = hh - dh;   // compile-time
                        if (cc >= 0 && cc < CMAX_) {
                            #pragma unroll
                            for (int dw = 0; dw < 5; ++dw)
                                zacc[cc] = fmaf(Wk[dh + 2][dw], w[dw], zacc[cc]);
                        }
                    }
                }
            }
        }

        float avg_num = 0.f, den = 0.f, mx = -3.402823466e38f;
        int anyv = 0;
        const int pl0 = (p < P0), pl1 = (p < P1), pl2 = (p < P2);
        #pragma unroll
        for (int cc = 0; cc < CMAX_; ++cc) {
            if (cc < cymax) {               // uniform guard
                int m0 = (cc < cy0) & pl0;
                int m1 = (cc < cy1) & pl1;
                int m2 = (cc < cy2) & pl2;
                int a0 = bs0 + cc * P0 + p; a0 = a0 > 511 ? 511 : a0;
                int a1 = bs1 + cc * P1 + p; a1 = a1 > 511 ? 511 : a1;
                int a2 = bs2 + cc * P2 + p; a2 = a2 > 511 ? 511 : a2;
                float x0 = m0 ? row[a0] : 0.f;
                float x1 = m1 ? row[a1] : 0.f;
                float x2 = m2 ? row[a2] : 0.f;
                float res = fmaf(wr0, x0, fmaf(wr1, x1, fmaf(wr2, x2, bres)));
                float z = gelu_exact(zacc[cc]) + res;
                int mm = m0 | m1 | m2;
                float cm = mm ? 1.f : 0.f;
                avg_num += z * cm;
                den += cm;
                mx = mm ? fmaxf(mx, z) : mx;
                anyv |= mm;
            }
        }
        float avg = avg_num / (den + FEPS);
        float mpool = anyv ? mx : 0.f;

        float seq = 0.f;
        #pragma unroll 1
        for (int k = 0; k < 3; ++k) {
            const int P = Pk[k];
            if (pc >= P) continue;
            const int cy = cykA[k];
            const int bs = bskA[k];
            float s = 0.f;
            for (int c2i = 0; c2i < cy; ++c2i) {
                int a = bs + c2i * P + p; a = a > 511 ? 511 : a;
                s += ((p < P) ? row[a] : 0.f);
            }
            float brk = (p < P) ? s / ((float)cy + FEPS) : 0.f;
            float bwk = (k == 0) ? bw0 : (k == 1 ? bw1 : bw2);
            seq = fmaf(bwk, brk, seq);
        }

        avg_out[r * T_ + p] = avg;
        max_out[r * T_ + p] = mpool;
        seq_out[r * T_ + p] = seq;
    }
}

// ---------- kernel 3: fuse GEMM + gelu ----------
// grid (16 t-tiles, 32 b), 256 threads, 64o x 32t tile, 2o x 4t micro.
__global__ __launch_bounds__(256) void fuse_kernel(
    const float* __restrict__ avgb, const float* __restrict__ maxb,
    const float* __restrict__ seqb,
    const float* __restrict__ wf, const float* __restrict__ bfu,
    float* __restrict__ out)
{
    __shared__ float wT[64][70];    // wT[c][o], pad keeps rows 8B-aligned
    __shared__ float Bt[64][40];    // Bt[c][t]
    const int tid = threadIdx.x;
    const int b = blockIdx.y;
    const int tt0 = blockIdx.x * 32;
    const int og = tid >> 3;        // 0..31
    const int tg = tid & 7;         // 0..7
    const int o0 = og * 2;
    const int t0 = tg * 4;

    float acc[2][4];
    #pragma unroll
    for (int i = 0; i < 2; ++i)
        #pragma unroll
        for (int j = 0; j < 4; ++j) acc[i][j] = 0.f;

    const float* srcs[3] = {avgb, maxb, seqb};
    for (int g = 0; g < 3; ++g) {
        const float* __restrict__ src = srcs[g];
        // x tile: 64c x 32t = 512 float4, 2 per thread
        #pragma unroll
        for (int it = 0; it < 2; ++it) {
            int idx = tid + it * 256;          // 0..511
            int c = idx >> 3, t4 = idx & 7;
            float4 vv = reinterpret_cast<const float4*>(
                            &src[(b * 64 + c) * 512 + tt0])[t4];
            *reinterpret_cast<float4*>(&Bt[c][t4 * 4]) = vv;
        }
        // W chunk: 64c x 64o, read coalesced in c
        #pragma unroll
        for (int it = 0; it < 16; ++it) {
            int i = tid + it * 256;            // 0..4095
            int c = i & 63, o = i >> 6;
            wT[c][o] = wf[o * 192 + g * 64 + c];
        }
        __syncthreads();
        for (int c = 0; c < 64; ++c) {
            float2 wv = *reinterpret_cast<const float2*>(&wT[c][o0]);
            float4 bv = *reinterpret_cast<const float4*>(&Bt[c][t0]);
            const float wa[2] = {wv.x, wv.y};
            const float ba[4] = {bv.x, bv.y, bv.z, bv.w};
            #pragma unroll
            for (int i = 0; i < 2; ++i)
                #pragma unroll
                for (int j = 0; j < 4; ++j)
                    acc[i][j] = fmaf(wa[i], ba[j], acc[i][j]);
        }
        __syncthreads();
    }
    #pragma unroll
    for (int i = 0; i < 2; ++i) {
        float bias = bfu[o0 + i];
        float4 o4;
        o4.x = gelu_exact(acc[i][0] + bias);
        o4.y = gelu_exact(acc[i][1] + bias);
        o4.z = gelu_exact(acc[i][2] + bias);
        o4.w = gelu_exact(acc[i][3] + bias);
        *reinterpret_cast<float4*>(
            &out[(b * 64 + (o0 + i)) * 512 + tt0 + t0]) = o4;
    }
}

extern "C" void kernel_launch(void* const* d_in, const int* in_sizes, int n_in,
                              void* d_out, int out_size, void* d_ws, size_t ws_size,
                              hipStream_t stream) {
    const float* feat = (const float*)d_in[0];
    const float* w0  = (const float*)d_in[1];
    const float* b0  = (const float*)d_in[2];
    const float* w1  = (const float*)d_in[3];
    const float* b1  = (const float*)d_in[4];
    const float* w2  = (const float*)d_in[5];
    const float* b2  = (const float*)d_in[6];
    const float* wpj = (const float*)d_in[7];
    const float* bpj = (const float*)d_in[8];
    const float* wr  = (const float*)d_in[9];
    const float* br  = (const float*)d_in[10];
    const float* wf  = (const float*)d_in[11];
    const float* bfu = (const float*)d_in[12];

    float* ws = (float*)d_ws;
    float* avgb   = ws;
    float* maxb   = ws + (size_t)NROWS * T_;
    float* seqb   = ws + 2 * (size_t)NROWS * T_;
    float* params = ws + 3 * (size_t)NROWS * T_;

    dft_kernel<<<NROWS, 64, 0, stream>>>(feat, params);
    fold_kernel<<<NROWS, 64, 0, stream>>>(feat, params,
                                          w0, b0, w1, b1, w2, b2, wpj, bpj, wr, br,
                                          avgb, maxb, seqb);
    fuse_kernel<<<dim3(16, 32), 256, 0, stream>>>(avgb, maxb, seqb, wf, bfu,
                                                  (float*)d_out);
}